// Round 1
// baseline (689.120 us; speedup 1.0000x reference)
//
#include <hip/hip_runtime.h>
#include <math.h>

#define NN 100000
#define NE 3200000
#define FEA 67
#define HID 16
#define OUTC 2
#define KS 3
#define KH 48   /* KS*HID */
#define KO 6    /* KS*OUTC */
#define NB 98   /* ceil(NN/1024) */

// ---------------- degree / scan / CSR build ----------------

__global__ void k_deg(const int* __restrict__ dst, int* __restrict__ deg) {
    int e = blockIdx.x * 256 + threadIdx.x;
    if (e < NE) atomicAdd(&deg[dst[e]], 1);
}

__global__ void k_partial(const int* __restrict__ deg, int* __restrict__ partials) {
    __shared__ int s[256];
    int base = blockIdx.x * 1024;
    int acc = 0;
    for (int i = threadIdx.x; i < 1024; i += 256) {
        int idx = base + i;
        if (idx < NN) acc += deg[idx];
    }
    s[threadIdx.x] = acc;
    __syncthreads();
    for (int off = 128; off > 0; off >>= 1) {
        if (threadIdx.x < off) s[threadIdx.x] += s[threadIdx.x + off];
        __syncthreads();
    }
    if (threadIdx.x == 0) partials[blockIdx.x] = s[0];
}

__global__ void k_scan_partials(int* __restrict__ partials) {
    __shared__ int s[128];
    int t = threadIdx.x;
    int v0 = (t < NB) ? partials[t] : 0;
    s[t] = v0;
    __syncthreads();
    for (int off = 1; off < 128; off <<= 1) {
        int v = (t >= off) ? s[t - off] : 0;
        __syncthreads();
        s[t] += v;
        __syncthreads();
    }
    if (t < NB) partials[t] = s[t] - v0;   // exclusive prefix
}

__global__ void k_downsweep(const int* __restrict__ deg, const int* __restrict__ partials,
                            int* __restrict__ row_start, int* __restrict__ cursor,
                            float* __restrict__ dinv) {
    __shared__ int s[256];
    int base = blockIdx.x * 1024 + threadIdx.x * 4;
    int d0 = 0, d1 = 0, d2 = 0, d3 = 0;
    if (base + 0 < NN) d0 = deg[base + 0];
    if (base + 1 < NN) d1 = deg[base + 1];
    if (base + 2 < NN) d2 = deg[base + 2];
    if (base + 3 < NN) d3 = deg[base + 3];
    int ts = d0 + d1 + d2 + d3;
    s[threadIdx.x] = ts;
    __syncthreads();
    for (int off = 1; off < 256; off <<= 1) {
        int v = (threadIdx.x >= off) ? s[threadIdx.x - off] : 0;
        __syncthreads();
        s[threadIdx.x] += v;
        __syncthreads();
    }
    int excl = s[threadIdx.x] - ts + partials[blockIdx.x];
    int p[4];
    p[0] = excl; p[1] = excl + d0; p[2] = excl + d0 + d1; p[3] = excl + d0 + d1 + d2;
    int dv[4] = {d0, d1, d2, d3};
    #pragma unroll
    for (int q = 0; q < 4; ++q) {
        int idx = base + q;
        if (idx < NN) {
            row_start[idx] = p[q];
            cursor[idx]    = p[q];
            dinv[idx]      = (dv[q] > 0) ? rsqrtf((float)dv[q]) : 0.f;
        }
    }
}

__global__ void k_fill(const int* __restrict__ src, const int* __restrict__ dst,
                       const float* __restrict__ dinv, int* __restrict__ cursor,
                       int2* __restrict__ csr) {
    int e = blockIdx.x * 256 + threadIdx.x;
    if (e >= NE) return;
    int s = src[e], d = dst[e];
    float w = dinv[s] * dinv[d];
    int pos = atomicAdd(&cursor[d], 1);
    csr[pos] = make_int2(s, __float_as_int(w));
}

// ---------------- layer 1 dense transforms ----------------

// A[n][j] = sum_f x[n][f]*init_w1[k][f][h];  R[n][j] = sum_f x[n][f]*root_w1[k][f][h] + b1[j]
__global__ void k_transform1(const float* __restrict__ x, const float* __restrict__ iw,
                             const float* __restrict__ rw, const float* __restrict__ b1,
                             float* __restrict__ A, float* __restrict__ R) {
    __shared__ float xs[16 * FEA];           // 1072
    __shared__ float w0[KS * FEA * HID];     // 3216
    __shared__ float wr[KS * FEA * HID];     // 3216
    __shared__ float bb[KH];
    int n0 = blockIdx.x * 16;                // NN % 16 == 0 -> always full tile
    for (int i = threadIdx.x; i < KS * FEA * HID; i += 256) { w0[i] = iw[i]; wr[i] = rw[i]; }
    if (threadIdx.x < KH) bb[threadIdx.x] = b1[threadIdx.x];
    for (int i = threadIdx.x; i < 16 * FEA; i += 256) xs[i] = x[n0 * FEA + i];
    __syncthreads();
    for (int it = threadIdx.x; it < 16 * KH; it += 256) {
        int nl = it / KH, j = it % KH;
        int k = j >> 4, hh = j & 15;
        float a0 = 0.f, aR = bb[j];
        const float* wp0 = &w0[k * FEA * HID + hh];
        const float* wpr = &wr[k * FEA * HID + hh];
        const float* xp  = &xs[nl * FEA];
        #pragma unroll
        for (int f = 0; f < FEA; ++f) {
            float xv = xp[f];
            a0 += xv * wp0[f * HID];
            aR += xv * wpr[f * HID];
        }
        int n = n0 + nl;
        A[n * KH + j] = a0;
        R[n * KH + j] = aR;
    }
}

// A[n][k*16+p] = sum_h B[n][k*16+h] * w1[k][h][p]
__global__ void k_gemm16(const float* __restrict__ B, const float* __restrict__ w1,
                         float* __restrict__ A) {
    __shared__ float ws[KS * HID * HID];   // 768
    __shared__ float bt[16 * KH];          // 768
    int n0 = blockIdx.x * 16;
    for (int i = threadIdx.x; i < KS * HID * HID; i += 256) ws[i] = w1[i];
    for (int i = threadIdx.x; i < 16 * KH; i += 256) bt[i] = B[n0 * KH + i];
    __syncthreads();
    for (int it = threadIdx.x; it < 16 * KH; it += 256) {
        int nl = it / KH, j = it % KH;
        int k = j >> 4, p = j & 15;
        float acc = 0.f;
        const float* bp = &bt[nl * KH + k * HID];
        const float* wp = &ws[k * HID * HID + p];
        #pragma unroll
        for (int h = 0; h < HID; ++h) acc += bp[h] * wp[h * HID];
        A[(n0 + nl) * KH + j] = acc;
    }
}

// ---------------- SpMM propagate (gather, atomic-free) ----------------

template <bool RELU>
__global__ void k_spmm48(const float* __restrict__ Asrc, const float* __restrict__ R,
                         const int* __restrict__ row_start, const int* __restrict__ deg,
                         const int2* __restrict__ csr, float* __restrict__ Bout) {
    int wid  = (blockIdx.x * 256 + threadIdx.x) >> 6;   // one wave per node
    int lane = threadIdx.x & 63;
    if (lane >= KH) return;                              // grid is exact in nodes
    int start = row_start[wid];
    int d     = deg[wid];
    float acc = R[wid * KH + lane];
    int e = 0;
    for (; e + 4 <= d; e += 4) {
        int2 c0 = csr[start + e + 0];
        int2 c1 = csr[start + e + 1];
        int2 c2 = csr[start + e + 2];
        int2 c3 = csr[start + e + 3];
        float a0 = Asrc[c0.x * KH + lane];
        float a1 = Asrc[c1.x * KH + lane];
        float a2 = Asrc[c2.x * KH + lane];
        float a3 = Asrc[c3.x * KH + lane];
        acc += __int_as_float(c0.y) * a0;
        acc += __int_as_float(c1.y) * a1;
        acc += __int_as_float(c2.y) * a2;
        acc += __int_as_float(c3.y) * a3;
    }
    for (; e < d; ++e) {
        int2 c = csr[start + e];
        acc += __int_as_float(c.y) * Asrc[c.x * KH + lane];
    }
    if (RELU) acc = fmaxf(acc, 0.f);
    Bout[wid * KH + lane] = acc;
}

__global__ void k_spmm6(const float* __restrict__ Asrc, const float* __restrict__ R2,
                        const int* __restrict__ row_start, const int* __restrict__ deg,
                        const int2* __restrict__ csr, float* __restrict__ Bout) {
    int t = blockIdx.x * 256 + threadIdx.x;
    int node = t / KO, j = t % KO;
    if (node >= NN) return;
    int start = row_start[node];
    int d     = deg[node];
    float acc = R2[node * KO + j];
    int e = 0;
    for (; e + 4 <= d; e += 4) {
        int2 c0 = csr[start + e + 0];
        int2 c1 = csr[start + e + 1];
        int2 c2 = csr[start + e + 2];
        int2 c3 = csr[start + e + 3];
        acc += __int_as_float(c0.y) * Asrc[c0.x * KO + j];
        acc += __int_as_float(c1.y) * Asrc[c1.x * KO + j];
        acc += __int_as_float(c2.y) * Asrc[c2.x * KO + j];
        acc += __int_as_float(c3.y) * Asrc[c3.x * KO + j];
    }
    for (; e < d; ++e) {
        int2 c = csr[start + e];
        acc += __int_as_float(c.y) * Asrc[c.x * KO + j];
    }
    Bout[node * KO + j] = acc;
}

// ---------------- between-layer / layer-2 small kernels ----------------

__global__ void k_meanrelu(const float* __restrict__ B, float* __restrict__ H) {
    int t = blockIdx.x * 256 + threadIdx.x;   // grid exact: NN*HID/256
    int n = t >> 4, hh = t & 15;
    float v = (B[n * KH + hh] + B[n * KH + 16 + hh] + B[n * KH + 32 + hh]) * (1.f / 3.f);
    H[t] = fmaxf(v, 0.f);
}

__global__ void k_transform2(const float* __restrict__ H, const float* __restrict__ iw,
                             const float* __restrict__ rw, const float* __restrict__ b2,
                             float* __restrict__ A2, float* __restrict__ R2) {
    __shared__ float wi[KS * HID * OUTC];   // 96
    __shared__ float wr_[KS * HID * OUTC];  // 96
    __shared__ float bb[KO];
    if (threadIdx.x < KS * HID * OUTC) { wi[threadIdx.x] = iw[threadIdx.x]; wr_[threadIdx.x] = rw[threadIdx.x]; }
    if (threadIdx.x < KO) bb[threadIdx.x] = b2[threadIdx.x];
    __syncthreads();
    int n = blockIdx.x * 256 + threadIdx.x;
    if (n >= NN) return;
    float h[HID];
    const float4* hp = (const float4*)(H + n * HID);
    #pragma unroll
    for (int q = 0; q < 4; ++q) {
        float4 v = hp[q];
        h[q * 4 + 0] = v.x; h[q * 4 + 1] = v.y; h[q * 4 + 2] = v.z; h[q * 4 + 3] = v.w;
    }
    #pragma unroll
    for (int k = 0; k < KS; ++k) {
        #pragma unroll
        for (int o = 0; o < OUTC; ++o) {
            float a = 0.f, r = bb[k * 2 + o];
            #pragma unroll
            for (int hh = 0; hh < HID; ++hh) {
                a += h[hh] * wi[k * 32 + hh * 2 + o];
                r += h[hh] * wr_[k * 32 + hh * 2 + o];
            }
            A2[n * KO + k * 2 + o] = a;
            R2[n * KO + k * 2 + o] = r;
        }
    }
}

__global__ void k_gemm2(const float* __restrict__ B2, const float* __restrict__ w2,
                        float* __restrict__ A2) {
    __shared__ float ws[KS * OUTC * OUTC];  // 12
    if (threadIdx.x < KS * OUTC * OUTC) ws[threadIdx.x] = w2[threadIdx.x];
    __syncthreads();
    int n = blockIdx.x * 256 + threadIdx.x;
    if (n >= NN) return;
    float b[KO];
    #pragma unroll
    for (int i = 0; i < KO; ++i) b[i] = B2[n * KO + i];
    #pragma unroll
    for (int k = 0; k < KS; ++k) {
        #pragma unroll
        for (int p = 0; p < OUTC; ++p) {
            A2[n * KO + k * 2 + p] = b[k * 2 + 0] * ws[k * 4 + 0 * 2 + p]
                                   + b[k * 2 + 1] * ws[k * 4 + 1 * 2 + p];
        }
    }
}

__global__ void k_final(const float* __restrict__ B2, float* __restrict__ out) {
    int n = blockIdx.x * 256 + threadIdx.x;
    if (n >= NN) return;
    float o0 = (B2[n * KO + 0] + B2[n * KO + 2] + B2[n * KO + 4]) * (1.f / 3.f);
    float o1 = (B2[n * KO + 1] + B2[n * KO + 3] + B2[n * KO + 5]) * (1.f / 3.f);
    float m = fmaxf(o0, o1);
    float l = m + logf(expf(o0 - m) + expf(o1 - m));
    out[n * 2 + 0] = o0 - l;
    out[n * 2 + 1] = o1 - l;
}

// ---------------- host ----------------

extern "C" void kernel_launch(void* const* d_in, const int* in_sizes, int n_in,
                              void* d_out, int out_size, void* d_ws, size_t ws_size,
                              hipStream_t stream) {
    const float* x   = (const float*)d_in[0];
    const int*   ei  = (const int*)d_in[1];
    const float* iw1 = (const float*)d_in[2];
    const float* w1  = (const float*)d_in[3];
    const float* rw1 = (const float*)d_in[4];
    const float* b1  = (const float*)d_in[5];
    const float* iw2 = (const float*)d_in[6];
    const float* w2  = (const float*)d_in[7];
    const float* rw2 = (const float*)d_in[8];
    const float* b2  = (const float*)d_in[9];
    const int* src = ei;
    const int* dst = ei + NE;
    float* out = (float*)d_out;

    char* ws = (char*)d_ws;
    size_t o = 0;
    int*   deg       = (int*)(ws + o);   o += (size_t)NN * 4;            // 400000
    int*   row_start = (int*)(ws + o);   o += (size_t)NN * 4;
    int*   cursor    = (int*)(ws + o);   o += (size_t)NN * 4;
    float* dinv      = (float*)(ws + o); o += (size_t)NN * 4;            // 1,600,000
    int2*  csr       = (int2*)(ws + o);  o += (size_t)NE * 8;            // 27,200,000
    float* A         = (float*)(ws + o); o += (size_t)NN * KH * 4;       // 46,400,000
    float* R         = (float*)(ws + o); o += (size_t)NN * KH * 4;       // 65,600,000
    float* B         = (float*)(ws + o); o += (size_t)NN * KH * 4;       // 84,800,000
    int*   partials  = (int*)(ws + o);   o += 128 * 4;
    // overlays (regions free by the time these are used)
    float* H  = R;                        // N*16
    float* A2 = A;                        // N*6
    float* R2 = A + (size_t)NN * KO;      // N*6
    float* B2 = A + (size_t)NN * KO * 2;  // N*6

    hipMemsetAsync(deg, 0, (size_t)NN * 4, stream);
    k_deg<<<NE / 256, 256, 0, stream>>>(dst, deg);
    k_partial<<<NB, 256, 0, stream>>>(deg, partials);
    k_scan_partials<<<1, 128, 0, stream>>>(partials);
    k_downsweep<<<NB, 256, 0, stream>>>(deg, partials, row_start, cursor, dinv);
    k_fill<<<NE / 256, 256, 0, stream>>>(src, dst, dinv, cursor, csr);

    // layer 1
    k_transform1<<<NN / 16, 256, 0, stream>>>(x, iw1, rw1, b1, A, R);
    k_spmm48<true><<<NN / 4, 256, 0, stream>>>(A, R, row_start, deg, csr, B);
    k_gemm16<<<NN / 16, 256, 0, stream>>>(B, w1, A);
    k_spmm48<true><<<NN / 4, 256, 0, stream>>>(A, R, row_start, deg, csr, B);
    k_meanrelu<<<NN * HID / 256, 256, 0, stream>>>(B, H);

    // layer 2
    k_transform2<<<(NN + 255) / 256, 256, 0, stream>>>(H, iw2, rw2, b2, A2, R2);
    k_spmm6<<<(NN * KO + 255) / 256, 256, 0, stream>>>(A2, R2, row_start, deg, csr, B2);
    k_gemm2<<<(NN + 255) / 256, 256, 0, stream>>>(B2, w2, A2);
    k_spmm6<<<(NN * KO + 255) / 256, 256, 0, stream>>>(A2, R2, row_start, deg, csr, B2);
    k_final<<<(NN + 255) / 256, 256, 0, stream>>>(B2, out);
}